// Round 2
// baseline (503.768 us; speedup 1.0000x reference)
//
#include <hip/hip_runtime.h>

#define NB   32
#define NHIS 12
#define GDIM 307
#define EMBD 32
#define HIDD 384
#define IN_ROW 309
#define IN_B  (13*309)
#define NROWS (NB*GDIM)          // 9824

// ---------------- k_prep: A[b,t,i,j] = sum_e cw[e]*dw[date_b,t,e,i,j];
//                  Cb[b,i,j] = sum_{t,e} cb[e]*dw[...]
__global__ __launch_bounds__(256) void k_prep(const float* __restrict__ inp,
    const float* __restrict__ dws, const float* __restrict__ cw,
    const float* __restrict__ cb, float* __restrict__ A, float* __restrict__ Cb) {
  __shared__ float sC[4608];
  __shared__ float scw[32], scb[32];
  int b = blockIdx.x;
  if (threadIdx.x < 32) { scw[threadIdx.x] = cw[threadIdx.x]; scb[threadIdx.x] = cb[threadIdx.x]; }
  __syncthreads();
  int date = (int)inp[b*IN_B + 1];
  const float* dw = dws + (size_t)date * 147456;
  for (int idx = threadIdx.x; idx < 4608; idx += 256) {
    int t = idx / 384, r = idx - t*384;
    const float* p = dw + t*12288 + r;
    float sA = 0.f, sCv = 0.f;
    #pragma unroll
    for (int e = 0; e < 32; e++) {
      float v = p[e*384];
      sA  += scw[e] * v;
      sCv += scb[e] * v;
    }
    A[b*4608 + idx] = sA;
    sC[idx] = sCv;
  }
  __syncthreads();
  for (int r = threadIdx.x; r < 384; r += 256) {
    float s = 0.f;
    #pragma unroll
    for (int t = 0; t < 12; t++) s += sC[t*384 + r];
    Cb[b*384 + r] = s;
  }
}

// ---------------- k_l0: H[row,h] = relu(sum_t x3t[row,t]*w0[t,h] + b0[h])
__global__ __launch_bounds__(256) void k_l0(const float* __restrict__ inp,
    const float* __restrict__ w0, const float* __restrict__ b0, float* __restrict__ H) {
  int gid = blockIdx.x*256 + threadIdx.x;
  if (gid >= NROWS*HIDD) return;
  int row = gid / HIDD, h = gid - row*HIDD;
  int b = row / GDIM, g = row - b*GDIM;
  float acc = b0[h];
  #pragma unroll
  for (int t = 0; t < 12; t++) {
    float xv = inp[b*IN_B + (1+t)*IN_ROW + 2 + g];
    acc += xv * w0[t*HIDD + h];
  }
  H[gid] = fmaxf(acc, 0.f);
}

// ---------------- generic fp32 tiled GEMM: C = act(A@B + bias)
// BM=BN=64, BK=16, 256 threads, 4x4 micro-tile. Optional split-K via blockIdx.z.
template<int ACT, bool BVEC>
__global__ __launch_bounds__(256) void k_gemm(
    const float* __restrict__ A, int ldA,
    const float* __restrict__ B, int ldB,
    const float* __restrict__ bias,
    float* __restrict__ C, int ldC, long Cstride,
    int M, int N, int K, int kchunk) {
  __shared__ float As[16][64];
  __shared__ float Bs[16][64];
  int tid = threadIdx.x;
  int tx = tid & 15, ty = tid >> 4;
  int m0 = blockIdx.y * 64, n0 = blockIdx.x * 64;
  int z = blockIdx.z;
  int kstart = z * kchunk;
  int kend = min(K, kstart + kchunk);
  C += (long)z * Cstride;
  int arow = tid >> 2;
  int acol = (tid & 3) << 2;
  int brow = tid >> 4;
  int bcol = (tid & 15) << 2;
  float acc[4][4] = {};
  for (int k0 = kstart; k0 < kend; k0 += 16) {
    float4 av = make_float4(0.f,0.f,0.f,0.f);
    if (m0 + arow < M)
      av = *(const float4*)(A + (size_t)(m0+arow)*ldA + k0 + acol);
    As[acol+0][arow]=av.x; As[acol+1][arow]=av.y; As[acol+2][arow]=av.z; As[acol+3][arow]=av.w;
    float4 bv = make_float4(0.f,0.f,0.f,0.f);
    const float* bp = B + (size_t)(k0+brow)*ldB + n0 + bcol;
    if (BVEC) {
      if (n0 + bcol + 3 < N) bv = *(const float4*)bp;
      else {
        if (n0+bcol+0 < N) bv.x = bp[0];
        if (n0+bcol+1 < N) bv.y = bp[1];
        if (n0+bcol+2 < N) bv.z = bp[2];
      }
    } else {
      if (n0+bcol+0 < N) bv.x = bp[0];
      if (n0+bcol+1 < N) bv.y = bp[1];
      if (n0+bcol+2 < N) bv.z = bp[2];
      if (n0+bcol+3 < N) bv.w = bp[3];
    }
    *(float4*)&Bs[brow][bcol] = bv;
    __syncthreads();
    #pragma unroll
    for (int kk = 0; kk < 16; kk++) {
      float4 a4 = *(const float4*)&As[kk][ty<<2];
      float4 b4 = *(const float4*)&Bs[kk][tx<<2];
      float aa[4] = {a4.x,a4.y,a4.z,a4.w};
      float bb[4] = {b4.x,b4.y,b4.z,b4.w};
      #pragma unroll
      for (int i=0;i<4;i++)
        #pragma unroll
        for (int j=0;j<4;j++) acc[i][j] += aa[i]*bb[j];
    }
    __syncthreads();
  }
  #pragma unroll
  for (int i=0;i<4;i++) {
    int row = m0 + (ty<<2) + i;
    if (row >= M) continue;
    #pragma unroll
    for (int j=0;j<4;j++) {
      int col = n0 + (tx<<2) + j;
      if (col >= N) continue;
      float v = acc[i][j];
      if (bias) v += bias[col];
      if (ACT==1) v = fmaxf(v, 0.f);
      C[(size_t)row*ldC + col] = v;
    }
  }
}

// ---------------- k_xln: x = sum_t x3*A + Cb + db; LN over j; leaky; write xln + xlnT
__global__ __launch_bounds__(384) void k_xln(const float* __restrict__ inp,
    const float* __restrict__ dbs, const float* __restrict__ A,
    const float* __restrict__ Cb, const float* __restrict__ gamma,
    const float* __restrict__ beta, float* __restrict__ xln, float* __restrict__ xlnT) {
  __shared__ float xs[12];
  __shared__ float xbuf[384];
  int blk = blockIdx.x;
  int b = blk / GDIM, g = blk - b*GDIM;
  int tid = threadIdx.x;
  int date = (int)inp[b*IN_B + 1];
  if (tid < 12) xs[tid] = inp[b*IN_B + (1+tid)*IN_ROW + 2 + g];
  __syncthreads();
  int i = tid / 12, j = tid - i*12;
  float acc = Cb[b*384 + tid] + dbs[(size_t)date*117888 + g*384 + tid];
  const float* Ab = A + b*4608 + tid;
  #pragma unroll
  for (int t = 0; t < 12; t++) acc += xs[t] * Ab[t*384];
  xbuf[tid] = acc;
  __syncthreads();
  float m = 0.f;
  #pragma unroll
  for (int q=0;q<12;q++) m += xbuf[i*12+q];
  m *= (1.f/12.f);
  float v = 0.f;
  #pragma unroll
  for (int q=0;q<12;q++) { float d = xbuf[i*12+q]-m; v += d*d; }
  v *= (1.f/12.f);
  float y = (acc - m) * rsqrtf(v + 1e-3f) * gamma[j] + beta[j];
  y = (y >= 0.f) ? y : 0.3f*y;
  xln[(size_t)blk*384 + tid] = y;
  xlnT[((size_t)(b*12 + j)*GDIM + g)*32 + i] = y;
}

// ---------------- k_tgred: tg = sum_z tg_part[z]
__global__ __launch_bounds__(256) void k_tgred(const float* __restrict__ part, float* __restrict__ tg) {
  int gid = blockIdx.x*256 + threadIdx.x;
  if (gid >= 117888) return;
  float s = 0.f;
  #pragma unroll
  for (int z=0;z<8;z++) s += part[(size_t)z*117888 + gid];
  tg[gid] = s;
}

// ---------------- k_gt: gt[b,g',o] = sum_{t',e} gte2gt[t',e,o] * xln[b, p%307, e, p/307], p=g'*12+t'
__global__ __launch_bounds__(256) void k_gt(const float* __restrict__ xln,
    const float* __restrict__ g2g, float* __restrict__ gt) {
  __shared__ float w[4608];
  for (int idx = threadIdx.x; idx < 4608; idx += 256) w[idx] = g2g[idx];
  __syncthreads();
  int gid = blockIdx.x*256 + threadIdx.x;
  if (gid >= 117888) return;
  int b = gid / 3684, rem = gid - b*3684;
  int gp = rem / 12, o = rem - gp*12;
  float acc = 0.f;
  #pragma unroll
  for (int tp = 0; tp < 12; tp++) {
    int p = gp*12 + tp;
    int t2 = p / 307;
    int g2 = p - t2*307;
    const float* xp = xln + (size_t)(b*GDIM + g2)*384 + t2;
    const float* wp = w + tp*384 + o;
    #pragma unroll
    for (int e = 0; e < 32; e++)
      acc += wp[e*12] * xp[e*12];
  }
  gt[gid] = acc;
}

// ---------------- k_final: gates + fully_w + scale, transposed store
__global__ __launch_bounds__(256) void k_final(const float* __restrict__ tg,
    const float* __restrict__ gt, const float* __restrict__ x1,
    const float* __restrict__ x2, const float* __restrict__ fw,
    float* __restrict__ out) {
  __shared__ float w[288];
  // FIX: 288 > blockDim (256) — strided load, not single-conditional
  for (int idx = threadIdx.x; idx < 288; idx += 256) w[idx] = fw[idx];
  __syncthreads();
  int gid = blockIdx.x*256 + threadIdx.x;
  if (gid >= NROWS) return;
  int b = gid / GDIM, g = gid - b*GDIM;
  float g1[12], g2[12];
  #pragma unroll
  for (int n = 0; n < 12; n++) {
    float tv  = tg[(size_t)(b*12+n)*GDIM + g];
    float x1v = x1[(size_t)gid*12 + n];
    float gv  = gt[(size_t)gid*12 + n];
    float x2v = x2[(size_t)gid*12 + n];
    float s1 = 1.f/(1.f + __expf(-tv));
    float s2 = 1.f/(1.f + __expf(-gv));
    g1[n] = (tv + x1v)*s1;
    g2[n] = (gv + x2v)*s2;
  }
  #pragma unroll
  for (int o = 0; o < 12; o++) {
    float acc = 0.f;
    #pragma unroll
    for (int n = 0; n < 12; n++)
      acc += g1[n]*w[n*12+o] + g2[n]*w[(12+n)*12+o];
    out[(size_t)(b*12+o)*GDIM + g] = acc*50.f + 60.f;
  }
}

extern "C" void kernel_launch(void* const* d_in, const int* in_sizes, int n_in,
                              void* d_out, int out_size, void* d_ws, size_t ws_size,
                              hipStream_t stream) {
  const float* inp    = (const float*)d_in[0];
  const float* cw     = (const float*)d_in[1];
  const float* cb     = (const float*)d_in[2];
  const float* dws    = (const float*)d_in[3];
  const float* dbs    = (const float*)d_in[4];
  const float* ln_g   = (const float*)d_in[5];
  const float* ln_b   = (const float*)d_in[6];
  const float* tge2tg = (const float*)d_in[7];
  const float* gte2gt = (const float*)d_in[8];
  const float* fullyw = (const float*)d_in[9];
  const float* se[8];
  const float* te[8];
  for (int i = 0; i < 8; i++) { se[i] = (const float*)d_in[10+i]; te[i] = (const float*)d_in[18+i]; }
  float* out = (float*)d_out;

  float* ws  = (float*)d_ws;
  float* A   = ws;               // 147456
  float* Cb  = A   + 147456;     // 12288
  float* x1  = Cb  + 12288;      // 117888
  float* x2  = x1  + 117888;     // 117888
  float* tg  = x2  + 117888;     // 117888
  float* gt  = tg  + 117888;     // 117888
  float* tgp = gt  + 117888;     // 8*117888 = 943104
  float* ha  = tgp + 943104;     // 3772416
  float* hb  = ha  + 3772416;    // 3772416   total ~36.5 MB

  // date-gathered weight precompute
  k_prep<<<32, 256, 0, stream>>>(inp, dws, cw, cb, A, Cb);

  // SE MLP: x1
  k_l0<<<(NROWS*HIDD+255)/256, 256, 0, stream>>>(inp, se[0], se[1], ha);
  k_gemm<0,true><<<dim3(6,154,1), 256, 0, stream>>>(ha,384, se[2],384, se[3], hb,384,0, NROWS,384,384,384);
  k_gemm<1,true><<<dim3(6,154,1), 256, 0, stream>>>(hb,384, se[4],384, se[5], ha,384,0, NROWS,384,384,384);
  k_gemm<0,true><<<dim3(1,154,1), 256, 0, stream>>>(ha,384, se[6],12,  se[7], x1,12,0,  NROWS,12, 384,384);

  // TE MLP: x2
  k_l0<<<(NROWS*HIDD+255)/256, 256, 0, stream>>>(inp, te[0], te[1], ha);
  k_gemm<0,true><<<dim3(6,154,1), 256, 0, stream>>>(ha,384, te[2],384, te[3], hb,384,0, NROWS,384,384,384);
  k_gemm<1,true><<<dim3(6,154,1), 256, 0, stream>>>(hb,384, te[4],384, te[5], ha,384,0, NROWS,384,384,384);
  k_gemm<0,true><<<dim3(1,154,1), 256, 0, stream>>>(ha,384, te[6],12,  te[7], x2,12,0,  NROWS,12, 384,384);

  // x + LN + leaky -> xln (ha), xlnT (hb)
  k_xln<<<NROWS, 384, 0, stream>>>(inp, dbs, A, Cb, ln_g, ln_b, ha, hb);

  // tg = xlnT @ tge2tg  (M=384, N=307, K=9824, split-K=8 deterministic)
  k_gemm<0,false><<<dim3(5,6,8), 256, 0, stream>>>(hb,9824, tge2tg,307, nullptr, tgp,307,117888, 384,307,9824,1232);
  k_tgred<<<461, 256, 0, stream>>>(tgp, tg);

  // gt
  k_gt<<<461, 256, 0, stream>>>(ha, gte2gt, gt);

  // gates + output
  k_final<<<(NROWS+255)/256, 256, 0, stream>>>(tg, gt, x1, x2, fullyw, out);
}

// Round 3
// 277.416 us; speedup vs baseline: 1.8159x; 1.8159x over previous
//
#include <hip/hip_runtime.h>
#include <hip/hip_bf16.h>

#define NB   32
#define NHIS 12
#define GDIM 307
#define IN_ROW 309
#define IN_B  (13*309)
#define NROWS (NB*GDIM)          // 9824
#define MPAD  9856               // 77*128

typedef __attribute__((ext_vector_type(8))) short bf16x8;
typedef __attribute__((ext_vector_type(4))) float f32x4;

__device__ __forceinline__ void async_copy16(const void* g, void* l) {
  __builtin_amdgcn_global_load_lds(
      (const __attribute__((address_space(1))) void*)g,
      (__attribute__((address_space(3))) void*)l, 16, 0, 0);
}

// ---------------- k_prep: A[b,t,i,j] = sum_e cw[e]*dw[date_b,t,e,i,j];
//                  Cb[b,i,j] = sum_{t,e} cb[e]*dw[...]
__global__ __launch_bounds__(256) void k_prep(const float* __restrict__ inp,
    const float* __restrict__ dws, const float* __restrict__ cw,
    const float* __restrict__ cb, float* __restrict__ A, float* __restrict__ Cb) {
  __shared__ float sC[4608];
  __shared__ float scw[32], scb[32];
  int b = blockIdx.x;
  if (threadIdx.x < 32) { scw[threadIdx.x] = cw[threadIdx.x]; scb[threadIdx.x] = cb[threadIdx.x]; }
  __syncthreads();
  int date = (int)inp[b*IN_B + 1];
  const float* dw = dws + (size_t)date * 147456;
  for (int idx = threadIdx.x; idx < 4608; idx += 256) {
    int t = idx / 384, r = idx - t*384;
    const float* p = dw + t*12288 + r;
    float sA = 0.f, sCv = 0.f;
    #pragma unroll
    for (int e = 0; e < 32; e++) {
      float v = p[e*384];
      sA  += scw[e] * v;
      sCv += scb[e] * v;
    }
    A[b*4608 + idx] = sA;
    sC[idx] = sCv;
  }
  __syncthreads();
  for (int r = threadIdx.x; r < 384; r += 256) {
    float s = 0.f;
    #pragma unroll
    for (int t = 0; t < 12; t++) s += sC[t*384 + r];
    Cb[b*384 + r] = s;
  }
}

// ---------------- k_tr: dst[n][k] = bf16(src[k][n]); zero-fill OOB (pads)
__global__ __launch_bounds__(256) void k_tr(const float* __restrict__ src, int sK, int sN,
    __hip_bfloat16* __restrict__ dst, int dRows, int ldDst) {
  __shared__ float t[64][65];
  int k0 = blockIdx.x*64, n0 = blockIdx.y*64;
  int tx = threadIdx.x & 63, ty = threadIdx.x >> 6;
  for (int r = ty; r < 64; r += 4) {
    int k = k0 + r, n = n0 + tx;
    t[r][tx] = (k < sK && n < sN) ? src[(size_t)k*sN + n] : 0.f;
  }
  __syncthreads();
  for (int r = ty; r < 64; r += 4) {
    int n = n0 + r, k = k0 + tx;
    if (n < dRows && k < ldDst) dst[(size_t)n*ldDst + k] = __float2bfloat16(t[tx][r]);
  }
}

// ---------------- k_l0: H[row,h] = relu(sum_t x3t[row,t]*w0[t,h] + b0[h]) -> bf16
__global__ __launch_bounds__(256) void k_l0(const float* __restrict__ inp,
    const float* __restrict__ w0, const float* __restrict__ b0, __hip_bfloat16* __restrict__ H) {
  int gid = blockIdx.x*256 + threadIdx.x;
  if (gid >= NROWS*384) return;
  int row = gid / 384, h = gid - row*384;
  int b = row / GDIM, g = row - b*GDIM;
  float acc = b0[h];
  #pragma unroll
  for (int t = 0; t < 12; t++) {
    float xv = inp[b*IN_B + (1+t)*IN_ROW + 2 + g];
    acc += xv * w0[t*384 + h];
  }
  H[gid] = __float2bfloat16(fmaxf(acc, 0.f));
}

// ---------------- MFMA GEMM: C = act(A @ Bt^T + bias)
// A [M][ldA] bf16 row-major; Bt [N][ldB] bf16 (pre-transposed weights).
// Block tile 128(M) x 64(N), BK=64, 4 waves each 64x32 (4x2 frags of 16x16x32).
// XOR-swizzled LDS (chunk j ^= row&7) staged via global_load_lds w=16
// with pre-swizzled global source. Split-K via blockIdx.z (deterministic).
template<int ACT, int OUT_BF16>
__global__ __launch_bounds__(256) void k_mgemm(
    const __hip_bfloat16* __restrict__ A, int ldA,
    const __hip_bfloat16* __restrict__ Bt, int ldB,
    const float* __restrict__ bias,
    void* __restrict__ C, int ldC, long Czstride,
    int M, int N, int ktilesTotal, int kchunk) {
  __shared__ char smem[24576];   // A: 128x64 bf16 = 16KB @0; B: 64x64 bf16 = 8KB @16384
  const int tid = threadIdx.x;
  const int w = tid >> 6, lane = tid & 63;
  const int m0 = blockIdx.y * 128, n0 = blockIdx.x * 64;
  const int z = blockIdx.z;
  const int kt0 = z * kchunk;
  const int kt1 = min(ktilesTotal, kt0 + kchunk);

  f32x4 acc[4][2];
  #pragma unroll
  for (int i=0;i<4;i++)
    #pragma unroll
    for (int j=0;j<2;j++) acc[i][j] = (f32x4){0.f,0.f,0.f,0.f};

  const int wm = (w>>1)*64, wn = (w&1)*32;
  const int l15 = lane & 15, lhi = lane >> 4;

  for (int kt = kt0; kt < kt1; ++kt) {
    const int k0 = kt*64;
    // stage A: 1024 chunks of 16B; wave w, instr i covers chunks [w*256+i*64, +64)
    #pragma unroll
    for (int i=0;i<4;i++) {
      int c = w*256 + i*64 + lane;
      int row = c >> 3, j = c & 7;
      int jg = j ^ (row & 7);
      const __hip_bfloat16* src = A + (size_t)(m0+row)*ldA + k0 + jg*8;
      async_copy16(src, smem + (w*256 + i*64)*16);
    }
    // stage B: 512 chunks
    #pragma unroll
    for (int i=0;i<2;i++) {
      int c = w*128 + i*64 + lane;
      int row = c >> 3, j = c & 7;
      int jg = j ^ (row & 7);
      const __hip_bfloat16* src = Bt + (size_t)(n0+row)*ldB + k0 + jg*8;
      async_copy16(src, smem + 16384 + (w*128 + i*64)*16);
    }
    __syncthreads();
    #pragma unroll
    for (int kk=0;kk<2;kk++) {
      bf16x8 af[4], bfr[2];
      #pragma unroll
      for (int fi=0; fi<4; fi++) {
        int row = wm + fi*16 + l15;
        int off = row*128 + (((kk<<2)+lhi) ^ (row&7))*16;
        af[fi] = *(const bf16x8*)(smem + off);
      }
      #pragma unroll
      for (int fj=0; fj<2; fj++) {
        int n = wn + fj*16 + l15;
        int off = 16384 + n*128 + (((kk<<2)+lhi) ^ (n&7))*16;
        bfr[fj] = *(const bf16x8*)(smem + off);
      }
      #pragma unroll
      for (int fi=0;fi<4;fi++)
        #pragma unroll
        for (int fj=0;fj<2;fj++)
          acc[fi][fj] = __builtin_amdgcn_mfma_f32_16x16x32_bf16(af[fi], bfr[fj], acc[fi][fj], 0, 0, 0);
    }
    __syncthreads();
  }

  // epilogue: C/D layout col=lane&15, row=(lane>>4)*4+r
  #pragma unroll
  for (int fi=0;fi<4;fi++) {
    int row0 = m0 + wm + fi*16 + lhi*4;
    #pragma unroll
    for (int fj=0;fj<2;fj++) {
      int col = n0 + wn + fj*16 + l15;
      if (col < N) {
        float bv = bias ? bias[col] : 0.f;
        #pragma unroll
        for (int r=0;r<4;r++) {
          int row = row0 + r;
          if (row < M) {
            float v = acc[fi][fj][r] + bv;
            if (ACT==1) v = fmaxf(v, 0.f);
            if (OUT_BF16)
              ((__hip_bfloat16*)C)[(size_t)row*ldC + col] = __float2bfloat16(v);
            else
              ((float*)C + (size_t)z*Czstride)[(size_t)row*ldC + col] = v;
          }
        }
      }
    }
  }
}

// ---------------- k_xln: x = sum_t x3*A + Cb + db; LN over j; leaky; -> xln bf16 + xlnT bf16 (ld 9856)
__global__ __launch_bounds__(384) void k_xln(const float* __restrict__ inp,
    const float* __restrict__ dbs, const float* __restrict__ A,
    const float* __restrict__ Cb, const float* __restrict__ gamma,
    const float* __restrict__ beta, __hip_bfloat16* __restrict__ xln,
    __hip_bfloat16* __restrict__ xlnT) {
  __shared__ float xs[12];
  __shared__ float xbuf[384];
  int blk = blockIdx.x;
  int b = blk / GDIM, g = blk - b*GDIM;
  int tid = threadIdx.x;
  int date = (int)inp[b*IN_B + 1];
  if (tid < 12) xs[tid] = inp[b*IN_B + (1+tid)*IN_ROW + 2 + g];
  __syncthreads();
  int i = tid / 12, j = tid - i*12;
  float acc = Cb[b*384 + tid] + dbs[(size_t)date*117888 + g*384 + tid];
  const float* Ab = A + b*4608 + tid;
  #pragma unroll
  for (int t = 0; t < 12; t++) acc += xs[t] * Ab[t*384];
  xbuf[tid] = acc;
  __syncthreads();
  float m = 0.f;
  #pragma unroll
  for (int q=0;q<12;q++) m += xbuf[i*12+q];
  m *= (1.f/12.f);
  float v = 0.f;
  #pragma unroll
  for (int q=0;q<12;q++) { float d = xbuf[i*12+q]-m; v += d*d; }
  v *= (1.f/12.f);
  float y = (acc - m) * rsqrtf(v + 1e-3f) * gamma[j] + beta[j];
  y = (y >= 0.f) ? y : 0.3f*y;
  xln[(size_t)blk*384 + tid] = __float2bfloat16(y);
  xlnT[(size_t)(b*12 + j)*9856 + g*32 + i] = __float2bfloat16(y);
}

// ---------------- k_padzero: zero xlnT K-pad columns [9824,9856)
__global__ void k_padzero(__hip_bfloat16* __restrict__ xlnT) {
  xlnT[(size_t)blockIdx.x*9856 + 9824 + threadIdx.x] = __float2bfloat16(0.f);
}

// ---------------- k_tgred: tg = sum_z part[z]  (16 partials, 384x320)
__global__ __launch_bounds__(256) void k_tgred(const float* __restrict__ part, float* __restrict__ tg) {
  int gid = blockIdx.x*256 + threadIdx.x;
  if (gid >= 122880) return;
  float s = 0.f;
  #pragma unroll
  for (int z=0;z<16;z++) s += part[(size_t)z*122880 + gid];
  tg[gid] = s;
}

// ---------------- k_gt: gt[b,g',o] = sum_{t',e} gte2gt[t',e,o] * xln[b, p%307, e, p/307], p=g'*12+t'
__global__ __launch_bounds__(256) void k_gt(const __hip_bfloat16* __restrict__ xln,
    const float* __restrict__ g2g, float* __restrict__ gt) {
  __shared__ float w[4608];
  for (int idx = threadIdx.x; idx < 4608; idx += 256) w[idx] = g2g[idx];
  __syncthreads();
  int gid = blockIdx.x*256 + threadIdx.x;
  if (gid >= 117888) return;
  int b = gid / 3684, rem = gid - b*3684;
  int gp = rem / 12, o = rem - gp*12;
  float acc = 0.f;
  #pragma unroll
  for (int tp = 0; tp < 12; tp++) {
    int p = gp*12 + tp;
    int t2 = p / 307;
    int g2 = p - t2*307;
    const __hip_bfloat16* xp = xln + (size_t)(b*GDIM + g2)*384 + t2;
    const float* wp = w + tp*384 + o;
    #pragma unroll
    for (int e = 0; e < 32; e++)
      acc += wp[e*12] * __bfloat162float(xp[e*12]);
  }
  gt[gid] = acc;
}

// ---------------- k_final: gates + fully_w + scale, transposed store (tg ld=320)
__global__ __launch_bounds__(256) void k_final(const float* __restrict__ tg,
    const float* __restrict__ gt, const float* __restrict__ x1,
    const float* __restrict__ x2, const float* __restrict__ fw,
    float* __restrict__ out) {
  __shared__ float w[288];
  for (int idx = threadIdx.x; idx < 288; idx += 256) w[idx] = fw[idx];
  __syncthreads();
  int gid = blockIdx.x*256 + threadIdx.x;
  if (gid >= NROWS) return;
  int b = gid / GDIM, g = gid - b*GDIM;
  float g1[12], g2[12];
  #pragma unroll
  for (int n = 0; n < 12; n++) {
    float tv  = tg[(size_t)(b*12+n)*320 + g];
    float x1v = x1[(size_t)gid*12 + n];
    float gv  = gt[(size_t)gid*12 + n];
    float x2v = x2[(size_t)gid*12 + n];
    float s1 = 1.f/(1.f + __expf(-tv));
    float s2 = 1.f/(1.f + __expf(-gv));
    g1[n] = (tv + x1v)*s1;
    g2[n] = (gv + x2v)*s2;
  }
  #pragma unroll
  for (int o = 0; o < 12; o++) {
    float acc = 0.f;
    #pragma unroll
    for (int n = 0; n < 12; n++)
      acc += g1[n]*w[n*12+o] + g2[n]*w[(12+n)*12+o];
    out[(size_t)(b*12+o)*GDIM + g] = acc*50.f + 60.f;
  }
}

extern "C" void kernel_launch(void* const* d_in, const int* in_sizes, int n_in,
                              void* d_out, int out_size, void* d_ws, size_t ws_size,
                              hipStream_t stream) {
  const float* inp    = (const float*)d_in[0];
  const float* cw     = (const float*)d_in[1];
  const float* cb     = (const float*)d_in[2];
  const float* dws    = (const float*)d_in[3];
  const float* dbs    = (const float*)d_in[4];
  const float* ln_g   = (const float*)d_in[5];
  const float* ln_b   = (const float*)d_in[6];
  const float* tge2tg = (const float*)d_in[7];
  const float* gte2gt = (const float*)d_in[8];
  const float* fullyw = (const float*)d_in[9];
  const float* se[8];
  const float* te[8];
  for (int i = 0; i < 8; i++) { se[i] = (const float*)d_in[10+i]; te[i] = (const float*)d_in[18+i]; }
  float* out = (float*)d_out;

  // ---- workspace carve (33.2 MB total; round-2 footprint 36.5 MB fit) ----
  char* base = (char*)d_ws;
  size_t off = 0;
  auto alloc = [&](size_t bytes) { char* r = base + off; off += (bytes + 255) & ~(size_t)255; return r; };
  float* A_pre = (float*)alloc(147456*4);
  float* Cb    = (float*)alloc(12288*4);
  float* x1    = (float*)alloc(117888*4);
  float* x2    = (float*)alloc(117888*4);
  float* tgv   = (float*)alloc(122880*4);
  float* gtv   = (float*)alloc(117888*4);
  char*  uni   = alloc(1966080*4);           // union: hA (bf16 MPAD*384) / tgp (f32 16*122880)
  __hip_bfloat16* hA  = (__hip_bfloat16*)uni;
  float*          tgp = (float*)uni;
  __hip_bfloat16* hB   = (__hip_bfloat16*)alloc((size_t)MPAD*384*2);  // also xlnT (384 x 9856)
  __hip_bfloat16* xlnb = (__hip_bfloat16*)alloc((size_t)NROWS*384*2);
  __hip_bfloat16* Wse1 = (__hip_bfloat16*)alloc(147456*2);
  __hip_bfloat16* Wse2 = (__hip_bfloat16*)alloc(147456*2);
  __hip_bfloat16* Wte1 = (__hip_bfloat16*)alloc(147456*2);
  __hip_bfloat16* Wte2 = (__hip_bfloat16*)alloc(147456*2);
  __hip_bfloat16* Wse3 = (__hip_bfloat16*)alloc(24576*2);   // 64 x 384, rows 12.. zeroed
  __hip_bfloat16* Wte3 = (__hip_bfloat16*)alloc(24576*2);
  __hip_bfloat16* Wtg  = (__hip_bfloat16*)alloc((size_t)320*9856*2);  // zero-padded

  // date-gathered weight precompute (fp32 path for LN accuracy)
  k_prep<<<32, 256, 0, stream>>>(inp, dws, cw, cb, A_pre, Cb);

  // weight transposes -> bf16 [N][K]
  k_tr<<<dim3(6,6), 256, 0, stream>>>(se[2], 384, 384, Wse1, 384, 384);
  k_tr<<<dim3(6,6), 256, 0, stream>>>(se[4], 384, 384, Wse2, 384, 384);
  k_tr<<<dim3(6,6), 256, 0, stream>>>(te[2], 384, 384, Wte1, 384, 384);
  k_tr<<<dim3(6,6), 256, 0, stream>>>(te[4], 384, 384, Wte2, 384, 384);
  k_tr<<<dim3(6,1), 256, 0, stream>>>(se[6], 384, 12,  Wse3, 64,  384);
  k_tr<<<dim3(6,1), 256, 0, stream>>>(te[6], 384, 12,  Wte3, 64,  384);
  k_tr<<<dim3(154,5), 256, 0, stream>>>(tge2tg, 9824, 307, Wtg, 320, 9856);

  // SE MLP
  k_l0<<<(NROWS*384+255)/256, 256, 0, stream>>>(inp, se[0], se[1], hA);
  k_mgemm<0,1><<<dim3(6,77,1), 256, 0, stream>>>(hA, 384, Wse1, 384, se[3], hB, 384, 0, NROWS, 384, 6, 6);
  k_mgemm<1,1><<<dim3(6,77,1), 256, 0, stream>>>(hB, 384, Wse2, 384, se[5], hA, 384, 0, NROWS, 384, 6, 6);
  k_mgemm<0,0><<<dim3(1,77,1), 256, 0, stream>>>(hA, 384, Wse3, 384, se[7], x1, 12, 0, NROWS, 12, 6, 6);

  // TE MLP
  k_l0<<<(NROWS*384+255)/256, 256, 0, stream>>>(inp, te[0], te[1], hA);
  k_mgemm<0,1><<<dim3(6,77,1), 256, 0, stream>>>(hA, 384, Wte1, 384, te[3], hB, 384, 0, NROWS, 384, 6, 6);
  k_mgemm<1,1><<<dim3(6,77,1), 256, 0, stream>>>(hB, 384, Wte2, 384, te[5], hA, 384, 0, NROWS, 384, 6, 6);
  k_mgemm<0,0><<<dim3(1,77,1), 256, 0, stream>>>(hA, 384, Wte3, 384, te[7], x2, 12, 0, NROWS, 12, 6, 6);

  // xlnT K-pad zero (hB free after TE layer-2), then x + LN + leaky
  k_padzero<<<384, 32, 0, stream>>>(hB);
  k_xln<<<NROWS, 384, 0, stream>>>(inp, dbs, A_pre, Cb, ln_g, ln_b, xlnb, hB);

  // tg = xlnT @ Wtg^T : M=384, N=320, K=154 tiles, split-K z=16 (hA region free -> tgp)
  k_mgemm<0,0><<<dim3(5,3,16), 256, 0, stream>>>(hB, 9856, Wtg, 9856, nullptr,
                                                 tgp, 320, 122880, 384, 320, 154, 10);
  k_tgred<<<480, 256, 0, stream>>>(tgp, tgv);

  // gt
  k_gt<<<461, 256, 0, stream>>>(xlnb, gte2gt, gtv);

  // gates + output
  k_final<<<39, 256, 0, stream>>>(tgv, gtv, x1, x2, fullyw, out);
}

// Round 4
// 150.666 us; speedup vs baseline: 3.3436x; 1.8413x over previous
//
#include <hip/hip_runtime.h>
#include <hip/hip_bf16.h>

#define NB   32
#define GDIM 307
#define IN_ROW 309
#define IN_B  (13*309)
#define NROWS (NB*GDIM)          // 9824
#define MPAD  9856               // 77*128

typedef __attribute__((ext_vector_type(8))) short bf16x8;
typedef __attribute__((ext_vector_type(4))) float f32x4;

__device__ __forceinline__ void async_copy16(const void* g, void* l) {
  __builtin_amdgcn_global_load_lds(
      (const __attribute__((address_space(1))) void*)g,
      (__attribute__((address_space(3))) void*)l, 16, 0, 0);
}

// ---------------- k_prep: grid (32,12). A[b,t,r]=sum_e cw[e]*dw; Cp[b,t,r]=sum_e cb[e]*dw
__global__ __launch_bounds__(256) void k_prep(const float* __restrict__ inp,
    const float* __restrict__ dws, const float* __restrict__ cw,
    const float* __restrict__ cb, float* __restrict__ A, float* __restrict__ Cp) {
  __shared__ float scw[32], scb[32];
  int b = blockIdx.x, t = blockIdx.y;
  if (threadIdx.x < 32) { scw[threadIdx.x] = cw[threadIdx.x]; scb[threadIdx.x] = cb[threadIdx.x]; }
  __syncthreads();
  int date = (int)inp[b*IN_B + 1];
  const float* dw = dws + (size_t)date * 147456 + t*12288;
  for (int r = threadIdx.x; r < 384; r += 256) {
    float sA = 0.f, sC = 0.f;
    #pragma unroll
    for (int e = 0; e < 32; e++) {
      float v = dw[e*384 + r];
      sA += scw[e] * v;
      sC += scb[e] * v;
    }
    A[(b*12 + t)*384 + r]  = sA;
    Cp[(b*12 + t)*384 + r] = sC;
  }
}

// ---------------- k_trb: batched transpose dst[n][k]=bf16(src[k][n]), zero-pad OOB
__global__ __launch_bounds__(256) void k_trb(
    const float* se1, const float* se2, const float* te1, const float* te2,
    const float* se3, const float* te3, const float* g2g, const float* tgw,
    __hip_bfloat16* Wse1, __hip_bfloat16* Wse2, __hip_bfloat16* Wte1, __hip_bfloat16* Wte2,
    __hip_bfloat16* Wse3, __hip_bfloat16* Wte3, __hip_bfloat16* Wgt, __hip_bfloat16* Wtg) {
  __shared__ float t[64][65];
  int bid = blockIdx.x;
  const float* src; __hip_bfloat16* dst; int sK, sN, dR, ldD, bx, by;
  if (bid < 144) {
    int q = bid / 36, s = bid % 36; bx = s % 6; by = s / 6;
    src = q==0?se1 : q==1?se2 : q==2?te1 : te2;
    dst = q==0?Wse1: q==1?Wse2: q==2?Wte1: Wte2;
    sK = 384; sN = 384; dR = 384; ldD = 384;
  } else if (bid < 162) {
    int q = (bid-144)/6, s = (bid-144)%6; bx = s; by = 0;
    src = q==0?se3:q==1?te3:g2g;
    dst = q==0?Wse3:q==1?Wte3:Wgt;
    sK = 384; sN = 12; dR = 64; ldD = 384;
  } else {
    int s = bid - 162; bx = s % 154; by = s / 154;
    src = tgw; dst = Wtg; sK = 9824; sN = 307; dR = 320; ldD = 9856;
  }
  int k0 = bx*64, n0 = by*64;
  int tx = threadIdx.x & 63, ty = threadIdx.x >> 6;
  for (int r = ty; r < 64; r += 4) {
    int k = k0 + r, n = n0 + tx;
    t[r][tx] = (k < sK && n < sN) ? src[(size_t)k*sN + n] : 0.f;
  }
  __syncthreads();
  for (int r = ty; r < 64; r += 4) {
    int n = n0 + r, k = k0 + tx;
    if (n < dR && k < ldD) dst[(size_t)n*ldD + k] = __float2bfloat16(t[tx][r]);
  }
}

// ---------------- k_l0b: batched layer-0 (z=0 SE, z=1 TE)
__global__ __launch_bounds__(256) void k_l0b(const float* __restrict__ inp,
    const float* __restrict__ w0a, const float* __restrict__ b0a,
    const float* __restrict__ w0b, const float* __restrict__ b0b,
    __hip_bfloat16* __restrict__ Ha, __hip_bfloat16* __restrict__ Hb) {
  int z = blockIdx.y;
  const float* w0 = z ? w0b : w0a;
  const float* b0 = z ? b0b : b0a;
  __hip_bfloat16* H = z ? Hb : Ha;
  int gid = blockIdx.x*256 + threadIdx.x;
  if (gid >= NROWS*384) return;
  int row = gid / 384, h = gid - row*384;
  int b = row / GDIM, g = row - b*GDIM;
  float acc = b0[h];
  #pragma unroll
  for (int t = 0; t < 12; t++) {
    float xv = inp[b*IN_B + (1+t)*IN_ROW + 2 + g];
    acc += xv * w0[t*384 + h];
  }
  H[gid] = __float2bfloat16(fmaxf(acc, 0.f));
}

// ---------------- MFMA GEMM core (128x64 tile, BK=64, XOR-swizzled LDS, gload_lds w16)
struct GJob {
  const __hip_bfloat16* A;
  const __hip_bfloat16* Bt;
  const float* bias;
  void* C;
  int ldA, ldB, ldC, M, N, act, outbf;
};

__device__ __forceinline__ void mgemm_body(
    const __hip_bfloat16* __restrict__ A, int ldA,
    const __hip_bfloat16* __restrict__ Bt, int ldB,
    const float* bias, void* C, int ldC, long Czoff,
    int M, int N, int kt0, int kt1, int act, int outbf,
    char* smem, int m0, int n0) {
  const int tid = threadIdx.x;
  const int w = tid >> 6, lane = tid & 63;
  f32x4 acc[4][2];
  #pragma unroll
  for (int i=0;i<4;i++)
    #pragma unroll
    for (int j=0;j<2;j++) acc[i][j] = (f32x4){0.f,0.f,0.f,0.f};
  const int wm = (w>>1)*64, wn = (w&1)*32;
  const int l15 = lane & 15, lhi = lane >> 4;

  for (int kt = kt0; kt < kt1; ++kt) {
    const int k0 = kt*64;
    #pragma unroll
    for (int i=0;i<4;i++) {
      int c = w*256 + i*64 + lane;
      int row = c >> 3, j = c & 7;
      int jg = j ^ (row & 7);
      async_copy16(A + (size_t)(m0+row)*ldA + k0 + jg*8, smem + (w*256 + i*64)*16);
    }
    #pragma unroll
    for (int i=0;i<2;i++) {
      int c = w*128 + i*64 + lane;
      int row = c >> 3, j = c & 7;
      int jg = j ^ (row & 7);
      async_copy16(Bt + (size_t)(n0+row)*ldB + k0 + jg*8, smem + 16384 + (w*128 + i*64)*16);
    }
    __syncthreads();
    #pragma unroll
    for (int kk=0;kk<2;kk++) {
      bf16x8 af[4], bfr[2];
      #pragma unroll
      for (int fi=0; fi<4; fi++) {
        int row = wm + fi*16 + l15;
        af[fi] = *(const bf16x8*)(smem + row*128 + (((kk<<2)+lhi) ^ (row&7))*16);
      }
      #pragma unroll
      for (int fj=0; fj<2; fj++) {
        int n = wn + fj*16 + l15;
        bfr[fj] = *(const bf16x8*)(smem + 16384 + n*128 + (((kk<<2)+lhi) ^ (n&7))*16);
      }
      #pragma unroll
      for (int fi=0;fi<4;fi++)
        #pragma unroll
        for (int fj=0;fj<2;fj++)
          acc[fi][fj] = __builtin_amdgcn_mfma_f32_16x16x32_bf16(af[fi], bfr[fj], acc[fi][fj], 0, 0, 0);
    }
    __syncthreads();
  }

  #pragma unroll
  for (int fi=0;fi<4;fi++) {
    int row0 = m0 + wm + fi*16 + lhi*4;
    #pragma unroll
    for (int fj=0;fj<2;fj++) {
      int col = n0 + wn + fj*16 + l15;
      if (col < N) {
        float bv = bias ? bias[col] : 0.f;
        #pragma unroll
        for (int r=0;r<4;r++) {
          int row = row0 + r;
          if (row < M) {
            float v = acc[fi][fj][r] + bv;
            if (act) v = fmaxf(v, 0.f);
            if (outbf)
              ((__hip_bfloat16*)C)[(size_t)row*ldC + col] = __float2bfloat16(v);
            else
              ((float*)C + Czoff)[(size_t)row*ldC + col] = v;
          }
        }
      }
    }
  }
}

// batched (z selects job), no split-K
__global__ __launch_bounds__(256) void k_mgemmN(GJob j0, GJob j1, GJob j2, int ktiles) {
  __shared__ char smem[24576];
  GJob jb = (blockIdx.z==0) ? j0 : (blockIdx.z==1 ? j1 : j2);
  mgemm_body(jb.A, jb.ldA, jb.Bt, jb.ldB, jb.bias, jb.C, jb.ldC, 0,
             jb.M, jb.N, 0, ktiles, jb.act, jb.outbf,
             smem, blockIdx.y*128, blockIdx.x*64);
}

// single, split-K over z (deterministic partials)
__global__ __launch_bounds__(256) void k_mgemmS(
    const __hip_bfloat16* A, int ldA, const __hip_bfloat16* Bt, int ldB,
    float* C, int ldC, long Czstride, int M, int N, int ktiles, int kchunk) {
  __shared__ char smem[24576];
  int z = blockIdx.z;
  int kt0 = z*kchunk, kt1 = min(ktiles, kt0 + kchunk);
  mgemm_body(A, ldA, Bt, ldB, nullptr, C, ldC, (long)z*Czstride,
             M, N, kt0, kt1, 0, 0, smem, blockIdx.y*128, blockIdx.x*64);
}

// ---------------- k_xln: acc = sum_t(xs*A + Cp) + db; LN; leaky; -> xlnT bf16 + xg bf16
__global__ __launch_bounds__(384) void k_xln(const float* __restrict__ inp,
    const float* __restrict__ dbs, const float* __restrict__ A,
    const float* __restrict__ Cp, const float* __restrict__ gamma,
    const float* __restrict__ beta, __hip_bfloat16* __restrict__ xlnT,
    __hip_bfloat16* __restrict__ xg) {
  __shared__ float xs[12];
  __shared__ float xbuf[384];
  int blk = blockIdx.x;
  int b = blk / GDIM, g = blk - b*GDIM;
  int tid = threadIdx.x;
  if (blk < 384 && tid < 32)   // zero xlnT K-pad cols [9824,9856)
    xlnT[(size_t)blk*9856 + 9824 + tid] = __float2bfloat16(0.f);
  int date = (int)inp[b*IN_B + 1];
  if (tid < 12) xs[tid] = inp[b*IN_B + (1+tid)*IN_ROW + 2 + g];
  __syncthreads();
  int i = tid / 12, j = tid - i*12;
  float acc = dbs[(size_t)date*117888 + g*384 + tid];
  const float* Ab = A + b*4608 + tid;
  const float* Cb = Cp + b*4608 + tid;
  #pragma unroll
  for (int t = 0; t < 12; t++) acc += xs[t] * Ab[t*384] + Cb[t*384];
  xbuf[tid] = acc;
  __syncthreads();
  float m = 0.f;
  #pragma unroll
  for (int q=0;q<12;q++) m += xbuf[i*12+q];
  m *= (1.f/12.f);
  float v = 0.f;
  #pragma unroll
  for (int q=0;q<12;q++) { float d = xbuf[i*12+q]-m; v += d*d; }
  v *= (1.f/12.f);
  float y = (acc - m) * rsqrtf(v + 1e-3f) * gamma[j] + beta[j];
  y = (y >= 0.f) ? y : 0.3f*y;
  __hip_bfloat16 yb = __float2bfloat16(y);
  xlnT[(size_t)(b*12 + j)*9856 + g*32 + i] = yb;          // [b*12+j][g*32+i]
  int q = j*GDIM + g;                                      // = G*12 + T
  xg[(size_t)(b*GDIM + q/12)*384 + (q%12)*32 + i] = yb;    // [b*307+G][T*32+E]
}

// ---------------- k_final: sum tg partials (16) + gates + fully_w + scale
__global__ __launch_bounds__(256) void k_final(const float* __restrict__ tgp,
    const float* __restrict__ gt, const float* __restrict__ x1,
    const float* __restrict__ x2, const float* __restrict__ fw,
    float* __restrict__ out) {
  __shared__ float w[288];
  for (int idx = threadIdx.x; idx < 288; idx += 256) w[idx] = fw[idx];
  __syncthreads();
  int gid = blockIdx.x*256 + threadIdx.x;
  if (gid >= NROWS) return;
  int b = gid / GDIM, g = gid - b*GDIM;
  float g1[12], g2[12];
  #pragma unroll
  for (int n = 0; n < 12; n++) {
    float tv = 0.f;
    #pragma unroll
    for (int z = 0; z < 16; z++) tv += tgp[(size_t)z*122880 + (b*12+n)*320 + g];
    float x1v = x1[(size_t)gid*12 + n];
    float gv  = gt[(size_t)gid*12 + n];
    float x2v = x2[(size_t)gid*12 + n];
    float s1 = 1.f/(1.f + __expf(-tv));
    float s2 = 1.f/(1.f + __expf(-gv));
    g1[n] = (tv + x1v)*s1;
    g2[n] = (gv + x2v)*s2;
  }
  #pragma unroll
  for (int o = 0; o < 12; o++) {
    float acc = 0.f;
    #pragma unroll
    for (int n = 0; n < 12; n++)
      acc += g1[n]*w[n*12+o] + g2[n]*w[(12+n)*12+o];
    out[(size_t)(b*12+o)*GDIM + g] = acc*50.f + 60.f;
  }
}

extern "C" void kernel_launch(void* const* d_in, const int* in_sizes, int n_in,
                              void* d_out, int out_size, void* d_ws, size_t ws_size,
                              hipStream_t stream) {
  const float* inp    = (const float*)d_in[0];
  const float* cw     = (const float*)d_in[1];
  const float* cb     = (const float*)d_in[2];
  const float* dws    = (const float*)d_in[3];
  const float* dbs    = (const float*)d_in[4];
  const float* ln_g   = (const float*)d_in[5];
  const float* ln_b   = (const float*)d_in[6];
  const float* tge2tg = (const float*)d_in[7];
  const float* gte2gt = (const float*)d_in[8];
  const float* fullyw = (const float*)d_in[9];
  const float* se[8];
  const float* te[8];
  for (int i = 0; i < 8; i++) { se[i] = (const float*)d_in[10+i]; te[i] = (const float*)d_in[18+i]; }
  float* out = (float*)d_out;

  // ---- workspace carve (~40.5 MB) ----
  char* base = (char*)d_ws;
  size_t off = 0;
  auto alloc = [&](size_t bytes) { char* r = base + off; off += (bytes + 255) & ~(size_t)255; return r; };
  float* A_pre = (float*)alloc(147456*4);
  float* Cp    = (float*)alloc(147456*4);
  float* x1    = (float*)alloc(117888*4);
  float* x2    = (float*)alloc(117888*4);
  float* gtv   = (float*)alloc(117888*4);
  __hip_bfloat16* hA_se = (__hip_bfloat16*)alloc((size_t)MPAD*384*2);  // tgp aliases (spans into hA_te)
  __hip_bfloat16* hA_te = (__hip_bfloat16*)alloc((size_t)MPAD*384*2);
  __hip_bfloat16* hB_se = (__hip_bfloat16*)alloc((size_t)MPAD*384*2);  // xlnT aliases after L2
  __hip_bfloat16* hB_te = (__hip_bfloat16*)alloc((size_t)MPAD*384*2);  // xg aliases after L2
  float* tgp = (float*)hA_se;                       // 16*122880*4 = 7.86MB < 15.1MB
  __hip_bfloat16* xlnT = hB_se;                     // 384 x 9856
  __hip_bfloat16* xg   = hB_te;                     // MPAD x 384
  __hip_bfloat16* Wse1 = (__hip_bfloat16*)alloc(147456*2);
  __hip_bfloat16* Wse2 = (__hip_bfloat16*)alloc(147456*2);
  __hip_bfloat16* Wte1 = (__hip_bfloat16*)alloc(147456*2);
  __hip_bfloat16* Wte2 = (__hip_bfloat16*)alloc(147456*2);
  __hip_bfloat16* Wse3 = (__hip_bfloat16*)alloc(24576*2);
  __hip_bfloat16* Wte3 = (__hip_bfloat16*)alloc(24576*2);
  __hip_bfloat16* Wgt  = (__hip_bfloat16*)alloc(24576*2);
  __hip_bfloat16* Wtg  = (__hip_bfloat16*)alloc((size_t)320*9856*2);

  // 1. date-gathered weight precompute (384 blocks)
  k_prep<<<dim3(32,12), 256, 0, stream>>>(inp, dws, cw, cb, A_pre, Cp);

  // 2. all weight transposes, one launch (932 blocks)
  k_trb<<<932, 256, 0, stream>>>(se[2], se[4], te[2], te[4], se[6], te[6], gte2gt, tge2tg,
                                 Wse1, Wse2, Wte1, Wte2, Wse3, Wte3, Wgt, Wtg);

  // 3. layer-0 SE+TE
  k_l0b<<<dim3((NROWS*384+255)/256, 2), 256, 0, stream>>>(inp, se[0], se[1], te[0], te[1], hA_se, hA_te);

  // 4. layer-1 SE+TE
  {
    GJob a{hA_se, Wse1, se[3], hB_se, 384,384,384, NROWS,384, 0,1};
    GJob b{hA_te, Wte1, te[3], hB_te, 384,384,384, NROWS,384, 0,1};
    k_mgemmN<<<dim3(6,77,2), 256, 0, stream>>>(a, b, b, 6);
  }
  // 5. layer-2 SE+TE (relu)
  {
    GJob a{hB_se, Wse2, se[5], hA_se, 384,384,384, NROWS,384, 1,1};
    GJob b{hB_te, Wte2, te[5], hA_te, 384,384,384, NROWS,384, 1,1};
    k_mgemmN<<<dim3(6,77,2), 256, 0, stream>>>(a, b, b, 6);
  }

  // 6. x + LN + leaky -> xlnT (over hB_se) + xg (over hB_te)
  k_xln<<<NROWS, 384, 0, stream>>>(inp, dbs, A_pre, Cp, ln_g, ln_b, xlnT, xg);

  // 7. layer-3 SE+TE + gt einsum as GEMM
  {
    GJob a{hA_se, Wse3, se[7], x1,  384,384,12, NROWS,12, 0,0};
    GJob b{hA_te, Wte3, te[7], x2,  384,384,12, NROWS,12, 0,0};
    GJob c{xg,    Wgt,  nullptr, gtv, 384,384,12, NROWS,12, 0,0};
    k_mgemmN<<<dim3(1,77,3), 256, 0, stream>>>(a, b, c, 6);
  }

  // 8. tg = xlnT @ Wtg^T (M=384,N=320,K=154 tiles, split-K 16) -> tgp (over hA_se/te)
  k_mgemmS<<<dim3(5,3,16), 256, 0, stream>>>(xlnT, 9856, Wtg, 9856, tgp, 320, 122880, 384, 320, 154, 10);

  // 9. partial-sum + gates + output
  k_final<<<39, 256, 0, stream>>>(tgp, gtv, x1, x2, fullyw, out);
}

// Round 5
// 118.683 us; speedup vs baseline: 4.2446x; 1.2695x over previous
//
#include <hip/hip_runtime.h>
#include <hip/hip_bf16.h>

#define NB   32
#define GDIM 307
#define IN_ROW 309
#define IN_B  (13*309)
#define NROWS (NB*GDIM)          // 9824
#define MPAD  9856               // 77*128

typedef __attribute__((ext_vector_type(8))) short bf16x8;
typedef __attribute__((ext_vector_type(4))) float f32x4;

__device__ __forceinline__ void async_copy16(const void* g, void* l) {
  __builtin_amdgcn_global_load_lds(
      (const __attribute__((address_space(1))) void*)g,
      (__attribute__((address_space(3))) void*)l, 16, 0, 0);
}

// ============ MFMA GEMM core (128x64 tile, BK=64, XOR-swizzled LDS, gload_lds w16)
__device__ __forceinline__ void mgemm_body(
    const __hip_bfloat16* __restrict__ A, int ldA,
    const __hip_bfloat16* __restrict__ Bt, int ldB,
    const float* bias, void* C, int ldC, long Czoff,
    int M, int N, int kt0, int kt1, int act, int outbf,
    char* smem, int m0, int n0) {
  const int tid = threadIdx.x;
  const int w = tid >> 6, lane = tid & 63;
  f32x4 acc[4][2];
  #pragma unroll
  for (int i=0;i<4;i++)
    #pragma unroll
    for (int j=0;j<2;j++) acc[i][j] = (f32x4){0.f,0.f,0.f,0.f};
  const int wm = (w>>1)*64, wn = (w&1)*32;
  const int l15 = lane & 15, lhi = lane >> 4;

  for (int kt = kt0; kt < kt1; ++kt) {
    const int k0 = kt*64;
    #pragma unroll
    for (int i=0;i<4;i++) {
      int c = w*256 + i*64 + lane;
      int row = c >> 3, j = c & 7;
      int jg = j ^ (row & 7);
      async_copy16(A + (size_t)(m0+row)*ldA + k0 + jg*8, smem + (w*256 + i*64)*16);
    }
    #pragma unroll
    for (int i=0;i<2;i++) {
      int c = w*128 + i*64 + lane;
      int row = c >> 3, j = c & 7;
      int jg = j ^ (row & 7);
      async_copy16(Bt + (size_t)(n0+row)*ldB + k0 + jg*8, smem + 16384 + (w*128 + i*64)*16);
    }
    __syncthreads();
    #pragma unroll
    for (int kk=0;kk<2;kk++) {
      bf16x8 af[4], bfr[2];
      #pragma unroll
      for (int fi=0; fi<4; fi++) {
        int row = wm + fi*16 + l15;
        af[fi] = *(const bf16x8*)(smem + row*128 + (((kk<<2)+lhi) ^ (row&7))*16);
      }
      #pragma unroll
      for (int fj=0; fj<2; fj++) {
        int n = wn + fj*16 + l15;
        bfr[fj] = *(const bf16x8*)(smem + 16384 + n*128 + (((kk<<2)+lhi) ^ (n&7))*16);
      }
      #pragma unroll
      for (int fi=0;fi<4;fi++)
        #pragma unroll
        for (int fj=0;fj<2;fj++)
          acc[fi][fj] = __builtin_amdgcn_mfma_f32_16x16x32_bf16(af[fi], bfr[fj], acc[fi][fj], 0, 0, 0);
    }
    __syncthreads();
  }

  #pragma unroll
  for (int fi=0;fi<4;fi++) {
    int row0 = m0 + wm + fi*16 + lhi*4;
    #pragma unroll
    for (int fj=0;fj<2;fj++) {
      int col = n0 + wn + fj*16 + l15;
      if (col < N) {
        float bv = bias ? bias[col] : 0.f;
        #pragma unroll
        for (int r=0;r<4;r++) {
          int row = row0 + r;
          if (row < M) {
            float v = acc[fi][fj][r] + bv;
            if (act) v = fmaxf(v, 0.f);
            if (outbf)
              ((__hip_bfloat16*)C)[(size_t)row*ldC + col] = __float2bfloat16(v);
            else
              ((float*)C + Czoff)[(size_t)row*ldC + col] = v;
          }
        }
      }
    }
  }
}

// ============ F1: trb [0,932) + l0 [932,3388) + prep [3388,3772)
__global__ __launch_bounds__(256) void k_f1(
    const float* __restrict__ inp, const float* __restrict__ dws,
    const float* __restrict__ cw, const float* __restrict__ cb,
    float* __restrict__ A_pre, float* __restrict__ Cp,
    const float* se1, const float* se2, const float* te1, const float* te2,
    const float* se3, const float* te3, const float* g2g, const float* tgw,
    __hip_bfloat16* Wse1, __hip_bfloat16* Wse2, __hip_bfloat16* Wte1, __hip_bfloat16* Wte2,
    __hip_bfloat16* Wse3, __hip_bfloat16* Wte3, __hip_bfloat16* Wgt, __hip_bfloat16* Wtg,
    const float* se0, const float* seb0, const float* te0, const float* teb0,
    __hip_bfloat16* __restrict__ hA_se, __hip_bfloat16* __restrict__ hA_te) {
  __shared__ char smem[20864];
  int bid = blockIdx.x, tid = threadIdx.x;
  if (bid < 932) {
    // ---- transpose: dst[n][k] = bf16(src[k][n]), zero-pad OOB
    float (*t)[65] = (float(*)[65])smem;
    const float* src; __hip_bfloat16* dst; int sK, sN, dR, ldD, bx, by;
    if (bid < 144) {
      int q = bid / 36, s = bid % 36; bx = s % 6; by = s / 6;
      src = q==0?se1 : q==1?se2 : q==2?te1 : te2;
      dst = q==0?Wse1: q==1?Wse2: q==2?Wte1: Wte2;
      sK = 384; sN = 384; dR = 384; ldD = 384;
    } else if (bid < 162) {
      int q = (bid-144)/6, s = (bid-144)%6; bx = s; by = 0;
      src = q==0?se3:q==1?te3:g2g;
      dst = q==0?Wse3:q==1?Wte3:Wgt;
      sK = 384; sN = 12; dR = 64; ldD = 384;
    } else {
      int s = bid - 162; bx = s % 154; by = s / 154;
      src = tgw; dst = Wtg; sK = 9824; sN = 307; dR = 320; ldD = 9856;
    }
    int k0 = bx*64, n0 = by*64;
    int tx = tid & 63, ty = tid >> 6;
    for (int r = ty; r < 64; r += 4) {
      int k = k0 + r, n = n0 + tx;
      t[r][tx] = (k < sK && n < sN) ? src[(size_t)k*sN + n] : 0.f;
    }
    __syncthreads();
    for (int r = ty; r < 64; r += 4) {
      int n = n0 + r, k = k0 + tx;
      if (n < dR && k < ldD) dst[(size_t)n*ldD + k] = __float2bfloat16(t[tx][r]);
    }
  } else if (bid < 3388) {
    // ---- layer-0: H[row,h] = relu(sum_t x3t[row,t]*w0[t,h] + b0[h]); 8 rows/block
    int idx = bid - 932;
    int z = idx / 1228, blkr = idx - z*1228;
    int r0 = blkr * 8;
    const float* w0 = z ? te0 : se0;
    const float* b0 = z ? teb0 : seb0;
    __hip_bfloat16* H = z ? hA_te : hA_se;
    float* sw = (float*)smem;          // 4608
    float* sb = sw + 4608;             // 384
    float* sx = sb + 384;              // 96
    for (int i = tid; i < 4608; i += 256) sw[i] = w0[i];
    for (int i = tid; i < 384; i += 256) sb[i] = b0[i];
    if (tid < 96) {
      int q = tid / 12, t = tid - q*12;
      int row = r0 + q, b = row / GDIM, g = row - b*GDIM;
      sx[tid] = inp[b*IN_B + (1+t)*IN_ROW + 2 + g];
    }
    __syncthreads();
    for (int h = tid; h < 384; h += 256) {
      float wv[12];
      #pragma unroll
      for (int t = 0; t < 12; t++) wv[t] = sw[t*384 + h];
      float bvv = sb[h];
      #pragma unroll
      for (int q = 0; q < 8; q++) {
        float acc = bvv;
        #pragma unroll
        for (int t = 0; t < 12; t++) acc += sx[q*12+t] * wv[t];
        H[(size_t)(r0+q)*384 + h] = __float2bfloat16(fmaxf(acc, 0.f));
      }
    }
  } else {
    // ---- prep: A[b,t,r]=sum_e cw[e]*dw; Cp[b,t,r]=sum_e cb[e]*dw
    int idx = bid - 3388;
    int b = idx / 12, t = idx - b*12;
    float* scw = (float*)smem;
    float* scb = scw + 32;
    if (tid < 32) { scw[tid] = cw[tid]; scb[tid] = cb[tid]; }
    __syncthreads();
    int date = (int)inp[b*IN_B + 1];
    const float* dw = dws + (size_t)date * 147456 + t*12288;
    for (int r = tid; r < 384; r += 256) {
      float sA = 0.f, sC = 0.f;
      #pragma unroll
      for (int e = 0; e < 32; e++) {
        float v = dw[e*384 + r];
        sA += scw[e] * v;
        sC += scb[e] * v;
      }
      A_pre[(b*12 + t)*384 + r] = sA;
      Cp[(b*12 + t)*384 + r]    = sC;
    }
  }
}

// ============ F2: L1 GEMM se/te [0,924) + xln [924,10748)
__global__ __launch_bounds__(256) void k_f2(
    const __hip_bfloat16* __restrict__ hA_se, const __hip_bfloat16* __restrict__ hA_te,
    const __hip_bfloat16* __restrict__ Wse1, const __hip_bfloat16* __restrict__ Wte1,
    const float* __restrict__ seb1, const float* __restrict__ teb1,
    __hip_bfloat16* __restrict__ hB_se, __hip_bfloat16* __restrict__ hB_te,
    const float* __restrict__ inp, const float* __restrict__ dbs,
    const float* __restrict__ A_pre, const float* __restrict__ Cp,
    const float* __restrict__ gamma, const float* __restrict__ beta,
    __hip_bfloat16* __restrict__ xlnT, __hip_bfloat16* __restrict__ xg) {
  __shared__ char smem[24576];
  int bid = blockIdx.x, tid = threadIdx.x;
  if (bid < 924) {
    int z = bid / 462, rem = bid - z*462;
    int n0 = (rem % 6)*64, m0 = (rem / 6)*128;
    mgemm_body(z ? hA_te : hA_se, 384, z ? Wte1 : Wse1, 384,
               z ? teb1 : seb1, z ? hB_te : hB_se, 384, 0,
               NROWS, 384, 0, 6, 0, 1, smem, m0, n0);
  } else {
    int blk = bid - 924;
    float* xs = (float*)smem;       // 12
    float* xbuf = xs + 16;          // 384
    int b = blk / GDIM, g = blk - b*GDIM;
    if (blk < 384 && tid < 32)
      xlnT[(size_t)blk*9856 + 9824 + tid] = __float2bfloat16(0.f);
    int date = (int)inp[b*IN_B + 1];
    if (tid < 12) xs[tid] = inp[b*IN_B + (1+tid)*IN_ROW + 2 + g];
    __syncthreads();
    float accv[2] = {0.f, 0.f};
    #pragma unroll
    for (int s = 0; s < 2; s++) {
      int e = tid + s*256;
      if (e < 384) {
        float acc = dbs[(size_t)date*117888 + g*384 + e];
        const float* Ab = A_pre + b*4608 + e;
        const float* Cb = Cp + b*4608 + e;
        #pragma unroll
        for (int t = 0; t < 12; t++) acc += xs[t]*Ab[t*384] + Cb[t*384];
        accv[s] = acc;
        xbuf[e] = acc;
      }
    }
    __syncthreads();
    #pragma unroll
    for (int s = 0; s < 2; s++) {
      int e = tid + s*256;
      if (e < 384) {
        int i = e / 12, j = e - i*12;
        float m = 0.f;
        #pragma unroll
        for (int q=0;q<12;q++) m += xbuf[i*12+q];
        m *= (1.f/12.f);
        float v = 0.f;
        #pragma unroll
        for (int q=0;q<12;q++) { float d = xbuf[i*12+q]-m; v += d*d; }
        v *= (1.f/12.f);
        float y = (accv[s] - m) * rsqrtf(v + 1e-3f) * gamma[j] + beta[j];
        y = (y >= 0.f) ? y : 0.3f*y;
        __hip_bfloat16 yb = __float2bfloat16(y);
        xlnT[(size_t)(b*12 + j)*9856 + g*32 + i] = yb;
        int q2 = j*GDIM + g;
        xg[(size_t)(b*GDIM + q2/12)*384 + (q2%12)*32 + i] = yb;
      }
    }
  }
}

// ============ F3: L2 GEMM se/te [0,924) + tg splitK [924,1164) + gt [1164,1241)
__global__ __launch_bounds__(256) void k_f3(
    const __hip_bfloat16* __restrict__ hB_se, const __hip_bfloat16* __restrict__ hB_te,
    const __hip_bfloat16* __restrict__ Wse2, const __hip_bfloat16* __restrict__ Wte2,
    const float* __restrict__ seb2, const float* __restrict__ teb2,
    __hip_bfloat16* __restrict__ hA_se, __hip_bfloat16* __restrict__ hA_te,
    const __hip_bfloat16* __restrict__ xlnT, const __hip_bfloat16* __restrict__ Wtg,
    float* __restrict__ tgp,
    const __hip_bfloat16* __restrict__ xg, const __hip_bfloat16* __restrict__ Wgt,
    float* __restrict__ gtv) {
  __shared__ char smem[24576];
  int bid = blockIdx.x;
  if (bid < 924) {
    int z = bid / 462, rem = bid - z*462;
    int n0 = (rem % 6)*64, m0 = (rem / 6)*128;
    mgemm_body(z ? hB_te : hB_se, 384, z ? Wte2 : Wse2, 384,
               z ? teb2 : seb2, z ? hA_te : hA_se, 384, 0,
               NROWS, 384, 0, 6, 1, 1, smem, m0, n0);
  } else if (bid < 1164) {
    int idx = bid - 924;
    int z = idx / 15, rem = idx - z*15;
    int n0 = (rem % 5)*64, m0 = (rem / 5)*128;
    int kt0 = z*10, kt1 = min(154, kt0 + 10);
    mgemm_body(xlnT, 9856, Wtg, 9856, nullptr, tgp, 320, (long)z*122880,
               384, 320, kt0, kt1, 0, 0, smem, m0, n0);
  } else {
    int m0 = (bid - 1164)*128;
    mgemm_body(xg, 384, Wgt, 384, nullptr, gtv, 12, 0,
               NROWS, 12, 0, 6, 0, 0, smem, m0, 0);
  }
}

// ============ F4: L3 GEMM se/te (154 blocks)
__global__ __launch_bounds__(256) void k_f4(
    const __hip_bfloat16* __restrict__ hA_se, const __hip_bfloat16* __restrict__ hA_te,
    const __hip_bfloat16* __restrict__ Wse3, const __hip_bfloat16* __restrict__ Wte3,
    const float* __restrict__ seb3, const float* __restrict__ teb3,
    float* __restrict__ x1, float* __restrict__ x2) {
  __shared__ char smem[24576];
  int bid = blockIdx.x;
  int z = bid / 77, m0 = (bid - z*77)*128;
  mgemm_body(z ? hA_te : hA_se, 384, z ? Wte3 : Wse3, 384,
             z ? teb3 : seb3, z ? x2 : x1, 12, 0,
             NROWS, 12, 0, 6, 0, 0, smem, m0, 0);
}

// ============ F5: sum tg partials (16) + gates + fully_w + scale
__global__ __launch_bounds__(256) void k_final(const float* __restrict__ tgp,
    const float* __restrict__ gt, const float* __restrict__ x1,
    const float* __restrict__ x2, const float* __restrict__ fw,
    float* __restrict__ out) {
  __shared__ float w[288];
  for (int idx = threadIdx.x; idx < 288; idx += 256) w[idx] = fw[idx];
  __syncthreads();
  int gid = blockIdx.x*256 + threadIdx.x;
  if (gid >= NROWS) return;
  int b = gid / GDIM, g = gid - b*GDIM;
  float g1[12], g2[12];
  #pragma unroll
  for (int n = 0; n < 12; n++) {
    float tv = 0.f;
    #pragma unroll
    for (int z = 0; z < 16; z++) tv += tgp[(size_t)z*122880 + (b*12+n)*320 + g];
    float x1v = x1[(size_t)gid*12 + n];
    float gv  = gt[(size_t)gid*12 + n];
    float x2v = x2[(size_t)gid*12 + n];
    float s1 = 1.f/(1.f + __expf(-tv));
    float s2 = 1.f/(1.f + __expf(-gv));
    g1[n] = (tv + x1v)*s1;
    g2[n] = (gv + x2v)*s2;
  }
  #pragma unroll
  for (int o = 0; o < 12; o++) {
    float acc = 0.f;
    #pragma unroll
    for (int n = 0; n < 12; n++)
      acc += g1[n]*w[n*12+o] + g2[n]*w[(12+n)*12+o];
    out[(size_t)(b*12+o)*GDIM + g] = acc*50.f + 60.f;
  }
}

extern "C" void kernel_launch(void* const* d_in, const int* in_sizes, int n_in,
                              void* d_out, int out_size, void* d_ws, size_t ws_size,
                              hipStream_t stream) {
  const float* inp    = (const float*)d_in[0];
  const float* cw     = (const float*)d_in[1];
  const float* cb     = (const float*)d_in[2];
  const float* dws    = (const float*)d_in[3];
  const float* dbs    = (const float*)d_in[4];
  const float* ln_g   = (const float*)d_in[5];
  const float* ln_b   = (const float*)d_in[6];
  const float* tge2tg = (const float*)d_in[7];
  const float* gte2gt = (const float*)d_in[8];
  const float* fullyw = (const float*)d_in[9];
  const float* se[8];
  const float* te[8];
  for (int i = 0; i < 8; i++) { se[i] = (const float*)d_in[10+i]; te[i] = (const float*)d_in[18+i]; }
  float* out = (float*)d_out;

  // ---- workspace carve (~63 MB, no aliasing) ----
  char* base = (char*)d_ws;
  size_t off = 0;
  auto alloc = [&](size_t bytes) { char* r = base + off; off += (bytes + 255) & ~(size_t)255; return r; };
  float* A_pre = (float*)alloc(147456*4);
  float* Cp    = (float*)alloc(147456*4);
  float* x1    = (float*)alloc(117888*4);
  float* x2    = (float*)alloc(117888*4);
  float* gtv   = (float*)alloc(117888*4);
  float* tgp   = (float*)alloc((size_t)16*122880*4);
  __hip_bfloat16* hA_se = (__hip_bfloat16*)alloc((size_t)MPAD*384*2);
  __hip_bfloat16* hA_te = (__hip_bfloat16*)alloc((size_t)MPAD*384*2);
  __hip_bfloat16* hB_se = (__hip_bfloat16*)alloc((size_t)MPAD*384*2);
  __hip_bfloat16* hB_te = (__hip_bfloat16*)alloc((size_t)MPAD*384*2);
  __hip_bfloat16* xlnT  = (__hip_bfloat16*)alloc((size_t)384*9856*2);
  __hip_bfloat16* xg    = (__hip_bfloat16*)alloc((size_t)MPAD*384*2);
  __hip_bfloat16* Wse1 = (__hip_bfloat16*)alloc(147456*2);
  __hip_bfloat16* Wse2 = (__hip_bfloat16*)alloc(147456*2);
  __hip_bfloat16* Wte1 = (__hip_bfloat16*)alloc(147456*2);
  __hip_bfloat16* Wte2 = (__hip_bfloat16*)alloc(147456*2);
  __hip_bfloat16* Wse3 = (__hip_bfloat16*)alloc(24576*2);
  __hip_bfloat16* Wte3 = (__hip_bfloat16*)alloc(24576*2);
  __hip_bfloat16* Wgt  = (__hip_bfloat16*)alloc(24576*2);
  __hip_bfloat16* Wtg  = (__hip_bfloat16*)alloc((size_t)320*9856*2);

  // F1: transposes + layer-0 + prep
  k_f1<<<3772, 256, 0, stream>>>(inp, dws, cw, cb, A_pre, Cp,
      se[2], se[4], te[2], te[4], se[6], te[6], gte2gt, tge2tg,
      Wse1, Wse2, Wte1, Wte2, Wse3, Wte3, Wgt, Wtg,
      se[0], se[1], te[0], te[1], hA_se, hA_te);

  // F2: L1 GEMMs + xln
  k_f2<<<10748, 256, 0, stream>>>(hA_se, hA_te, Wse1, Wte1, se[3], te[3],
      hB_se, hB_te, inp, dbs, A_pre, Cp, ln_g, ln_b, xlnT, xg);

  // F3: L2 GEMMs + tg split-K + gt
  k_f3<<<1241, 256, 0, stream>>>(hB_se, hB_te, Wse2, Wte2, se[5], te[5],
      hA_se, hA_te, xlnT, Wtg, tgp, xg, Wgt, gtv);

  // F4: L3 GEMMs
  k_f4<<<154, 256, 0, stream>>>(hA_se, hA_te, Wse3, Wte3, se[7], te[7], x1, x2);

  // F5: partial-sum + gates + output
  k_final<<<39, 256, 0, stream>>>(tgp, gtv, x1, x2, fullyw, out);
}

// Round 6
// 112.331 us; speedup vs baseline: 4.4847x; 1.0566x over previous
//
#include <hip/hip_runtime.h>
#include <hip/hip_bf16.h>

#define NB   32
#define GDIM 307
#define IN_ROW 309
#define IN_B  (13*309)
#define NROWS (NB*GDIM)          // 9824
#define MPAD  9856               // 77*128

typedef __attribute__((ext_vector_type(8))) short bf16x8;
typedef __attribute__((ext_vector_type(4))) float f32x4;

__device__ __forceinline__ void async_copy16(const void* g, void* l) {
  __builtin_amdgcn_global_load_lds(
      (const __attribute__((address_space(1))) void*)g,
      (__attribute__((address_space(3))) void*)l, 16, 0, 0);
}

// ============ MFMA GEMM core (128x64 tile, BK=64, XOR-swizzled LDS, gload_lds w16)
__device__ __forceinline__ void mgemm_body(
    const __hip_bfloat16* __restrict__ A, int ldA,
    const __hip_bfloat16* __restrict__ Bt, int ldB,
    const float* bias, void* C, int ldC, long Czoff,
    int M, int N, int kt0, int kt1, int act, int outbf,
    char* smem, int m0, int n0) {
  const int tid = threadIdx.x;
  const int w = tid >> 6, lane = tid & 63;
  f32x4 acc[4][2];
  #pragma unroll
  for (int i=0;i<4;i++)
    #pragma unroll
    for (int j=0;j<2;j++) acc[i][j] = (f32x4){0.f,0.f,0.f,0.f};
  const int wm = (w>>1)*64, wn = (w&1)*32;
  const int l15 = lane & 15, lhi = lane >> 4;

  for (int kt = kt0; kt < kt1; ++kt) {
    const int k0 = kt*64;
    #pragma unroll
    for (int i=0;i<4;i++) {
      int c = w*256 + i*64 + lane;
      int row = c >> 3, j = c & 7;
      int jg = j ^ (row & 7);
      async_copy16(A + (size_t)(m0+row)*ldA + k0 + jg*8, smem + (w*256 + i*64)*16);
    }
    #pragma unroll
    for (int i=0;i<2;i++) {
      int c = w*128 + i*64 + lane;
      int row = c >> 3, j = c & 7;
      int jg = j ^ (row & 7);
      async_copy16(Bt + (size_t)(n0+row)*ldB + k0 + jg*8, smem + 16384 + (w*128 + i*64)*16);
    }
    __syncthreads();
    #pragma unroll
    for (int kk=0;kk<2;kk++) {
      bf16x8 af[4], bfr[2];
      #pragma unroll
      for (int fi=0; fi<4; fi++) {
        int row = wm + fi*16 + l15;
        af[fi] = *(const bf16x8*)(smem + row*128 + (((kk<<2)+lhi) ^ (row&7))*16);
      }
      #pragma unroll
      for (int fj=0; fj<2; fj++) {
        int n = wn + fj*16 + l15;
        bfr[fj] = *(const bf16x8*)(smem + 16384 + n*128 + (((kk<<2)+lhi) ^ (n&7))*16);
      }
      #pragma unroll
      for (int fi=0;fi<4;fi++)
        #pragma unroll
        for (int fj=0;fj<2;fj++)
          acc[fi][fj] = __builtin_amdgcn_mfma_f32_16x16x32_bf16(af[fi], bfr[fj], acc[fi][fj], 0, 0, 0);
    }
    __syncthreads();
  }

  #pragma unroll
  for (int fi=0;fi<4;fi++) {
    int row0 = m0 + wm + fi*16 + lhi*4;
    #pragma unroll
    for (int fj=0;fj<2;fj++) {
      int col = n0 + wn + fj*16 + l15;
      if (col < N) {
        float bv = bias ? bias[col] : 0.f;
        #pragma unroll
        for (int r=0;r<4;r++) {
          int row = row0 + r;
          if (row < M) {
            float v = acc[fi][fj][r] + bv;
            if (act) v = fmaxf(v, 0.f);
            if (outbf)
              ((__hip_bfloat16*)C)[(size_t)row*ldC + col] = __float2bfloat16(v);
            else
              ((float*)C + Czoff)[(size_t)row*ldC + col] = v;
          }
        }
      }
    }
  }
}

// ============ F1: trb [0,932) + l0-chunk [932,1240) + prep [1240,1624)
__global__ __launch_bounds__(256) void k_f1(
    const float* __restrict__ inp, const float* __restrict__ dws,
    const float* __restrict__ cw, const float* __restrict__ cb,
    float* __restrict__ A_pre, float* __restrict__ Cp,
    const float* se1, const float* se2, const float* te1, const float* te2,
    const float* se3, const float* te3, const float* g2g, const float* tgw,
    __hip_bfloat16* Wse1, __hip_bfloat16* Wse2, __hip_bfloat16* Wte1, __hip_bfloat16* Wte2,
    __hip_bfloat16* Wse3, __hip_bfloat16* Wte3, __hip_bfloat16* Wgt, __hip_bfloat16* Wtg,
    const float* se0, const float* seb0, const float* te0, const float* teb0,
    __hip_bfloat16* __restrict__ hA_se, __hip_bfloat16* __restrict__ hA_te) {
  __shared__ char smem[23040];
  int bid = blockIdx.x, tid = threadIdx.x;
  if (bid < 932) {
    // ---- transpose: dst[n][k] = bf16(src[k][n]), zero-pad OOB
    float (*t)[65] = (float(*)[65])smem;
    const float* src; __hip_bfloat16* dst; int sK, sN, dR, ldD, bx, by;
    if (bid < 144) {
      int q = bid / 36, s = bid % 36; bx = s % 6; by = s / 6;
      src = q==0?se1 : q==1?se2 : q==2?te1 : te2;
      dst = q==0?Wse1: q==1?Wse2: q==2?Wte1: Wte2;
      sK = 384; sN = 384; dR = 384; ldD = 384;
    } else if (bid < 162) {
      int q = (bid-144)/6, s = (bid-144)%6; bx = s; by = 0;
      src = q==0?se3:q==1?te3:g2g;
      dst = q==0?Wse3:q==1?Wte3:Wgt;
      sK = 384; sN = 12; dR = 64; ldD = 384;
    } else {
      int s = bid - 162; bx = s % 154; by = s / 154;
      src = tgw; dst = Wtg; sK = 9824; sN = 307; dR = 320; ldD = 9856;
    }
    int k0 = bx*64, n0 = by*64;
    int tx = tid & 63, ty = tid >> 6;
    for (int r = ty; r < 64; r += 4) {
      int k = k0 + r, n = n0 + tx;
      t[r][tx] = (k < sK && n < sN) ? src[(size_t)k*sN + n] : 0.f;
    }
    __syncthreads();
    for (int r = ty; r < 64; r += 4) {
      int n = n0 + r, k = k0 + tx;
      if (n < dR && k < ldD) dst[(size_t)n*ldD + k] = __float2bfloat16(t[tx][r]);
    }
  } else if (bid < 1240) {
    // ---- layer-0, 64 rows/block: H[row,h] = relu(sum_t x3t[row,t]*w0[t,h]+b0[h])
    int idx = bid - 932;
    int z = idx / 154, mt = idx - z*154;
    int r0 = mt*64;
    const float* w0 = z ? te0 : se0;
    const float* b0 = z ? teb0 : seb0;
    __hip_bfloat16* H = z ? hA_te : hA_se;
    float* sw = (float*)smem;          // 4608
    float* sb = sw + 4608;             // 384
    float* sx = sb + 384;              // 768
    for (int i = tid; i < 4608; i += 256) sw[i] = w0[i];
    for (int i = tid; i < 384; i += 256) sb[i] = b0[i];
    for (int v = tid; v < 768; v += 256) {
      int r = v / 12, t = v - r*12;
      int row = r0 + r;
      float xv = 0.f;
      if (row < NROWS) {
        int b = row / GDIM, g = row - b*GDIM;
        xv = inp[b*IN_B + (1+t)*IN_ROW + 2 + g];
      }
      sx[v] = xv;
    }
    __syncthreads();
    for (int c = tid; c < 384; c += 256) {
      float wv[12];
      #pragma unroll
      for (int t = 0; t < 12; t++) wv[t] = sw[t*384 + c];
      float bv = sb[c];
      for (int r = 0; r < 64; r++) {
        int row = r0 + r;
        if (row >= NROWS) break;
        float acc = bv;
        #pragma unroll
        for (int t = 0; t < 12; t++) acc += sx[r*12+t] * wv[t];
        H[(size_t)row*384 + c] = __float2bfloat16(fmaxf(acc, 0.f));
      }
    }
  } else {
    // ---- prep: A[b,t,r]=sum_e cw[e]*dw; Cp[b,t,r]=sum_e cb[e]*dw
    int idx = bid - 1240;
    int b = idx / 12, t = idx - b*12;
    float* scw = (float*)smem;
    float* scb = scw + 32;
    if (tid < 32) { scw[tid] = cw[tid]; scb[tid] = cb[tid]; }
    __syncthreads();
    int date = (int)inp[b*IN_B + 1];
    const float* dw = dws + (size_t)date * 147456 + t*12288;
    for (int r = tid; r < 384; r += 256) {
      float sA = 0.f, sC = 0.f;
      #pragma unroll
      for (int e = 0; e < 32; e++) {
        float v = dw[e*384 + r];
        sA += scw[e] * v;
        sC += scb[e] * v;
      }
      A_pre[(b*12 + t)*384 + r] = sA;
      Cp[(b*12 + t)*384 + r]    = sC;
    }
  }
}

// ============ F2: L1 GEMM se/te [0,924) + xln-chunk [924,2172)
__global__ __launch_bounds__(256) void k_f2(
    const __hip_bfloat16* __restrict__ hA_se, const __hip_bfloat16* __restrict__ hA_te,
    const __hip_bfloat16* __restrict__ Wse1, const __hip_bfloat16* __restrict__ Wte1,
    const float* __restrict__ seb1, const float* __restrict__ teb1,
    __hip_bfloat16* __restrict__ hB_se, __hip_bfloat16* __restrict__ hB_te,
    const float* __restrict__ inp, const float* __restrict__ dbs,
    const float* __restrict__ A_pre, const float* __restrict__ Cp,
    const float* __restrict__ gamma, const float* __restrict__ beta,
    __hip_bfloat16* __restrict__ xlnT, __hip_bfloat16* __restrict__ xg) {
  __shared__ char smem[32640];
  int bid = blockIdx.x, tid = threadIdx.x;
  if (bid < 924) {
    int z = bid / 462, rem = bid - z*462;
    int n0 = (rem % 6)*64, m0 = (rem / 6)*128;
    mgemm_body(z ? hA_te : hA_se, 384, z ? Wte1 : Wse1, 384,
               z ? teb1 : seb1, z ? hB_te : hB_se, 384, 0,
               NROWS, 384, 0, 6, 0, 1, smem, m0, n0);
  } else {
    // xln: 8 g per block; 32 b x 39 chunks
    int idx = bid - 924;
    int b = idx / 39, gc = idx - b*39;
    int g0 = gc*8, ng = min(8, GDIM - g0);
    float* sA  = (float*)smem;          // 4608
    float* sxb = sA + 4608;             // 3072 (8x384)
    float* sCs = sxb + 3072;            // 384
    float* sx3 = sCs + 384;             // 96
    int date = (int)inp[b*IN_B + 1];
    for (int v = tid; v < 4608; v += 256) sA[v] = A_pre[b*4608 + v];
    for (int e = tid; e < 384; e += 256) {
      float s = 0.f;
      #pragma unroll
      for (int t = 0; t < 12; t++) s += Cp[b*4608 + t*384 + e];
      sCs[e] = s;
    }
    if (tid < ng*12) {
      int gl = tid / 12, t = tid - gl*12;
      sx3[tid] = inp[b*IN_B + (1+t)*IN_ROW + 2 + g0 + gl];
    }
    if (gc == 38) {  // zero xlnT K-pad cols [9824,9856) for this b's 12 rows
      for (int v = tid; v < 384; v += 256) {
        int j = v >> 5, c = v & 31;
        xlnT[(size_t)(b*12+j)*9856 + 9824 + c] = __float2bfloat16(0.f);
      }
    }
    __syncthreads();
    for (int o = tid; o < ng*384; o += 256) {
      int gl = o / 384, e = o - gl*384;
      float acc = sCs[e] + dbs[(size_t)date*117888 + (g0+gl)*384 + e];
      #pragma unroll
      for (int t = 0; t < 12; t++) acc += sx3[gl*12+t] * sA[t*384 + e];
      sxb[gl*384 + e] = acc;
    }
    __syncthreads();
    if (tid < ng*32) {
      int gl = tid >> 5, i = tid & 31;
      const float* xb = sxb + gl*384 + i*12;
      float m = 0.f;
      #pragma unroll
      for (int q = 0; q < 12; q++) m += xb[q];
      m *= (1.f/12.f);
      float v = 0.f;
      #pragma unroll
      for (int q = 0; q < 12; q++) { float d = xb[q] - m; v += d*d; }
      v *= (1.f/12.f);
      float rs = rsqrtf(v + 1e-3f);
      int g = g0 + gl;
      #pragma unroll
      for (int j = 0; j < 12; j++) {
        float y = (xb[j] - m) * rs * gamma[j] + beta[j];
        y = (y >= 0.f) ? y : 0.3f*y;
        __hip_bfloat16 yb = __float2bfloat16(y);
        xlnT[(size_t)(b*12 + j)*9856 + g*32 + i] = yb;
        int q2 = j*GDIM + g;
        int gq = q2 / 12, tq = q2 - gq*12;
        xg[(size_t)(b*GDIM + gq)*384 + tq*32 + i] = yb;
      }
    }
  }
}

// ============ F3: L2 GEMM se/te [0,924) + tg splitK [924,1164) + gt [1164,1241)
__global__ __launch_bounds__(256) void k_f3(
    const __hip_bfloat16* __restrict__ hB_se, const __hip_bfloat16* __restrict__ hB_te,
    const __hip_bfloat16* __restrict__ Wse2, const __hip_bfloat16* __restrict__ Wte2,
    const float* __restrict__ seb2, const float* __restrict__ teb2,
    __hip_bfloat16* __restrict__ hA_se, __hip_bfloat16* __restrict__ hA_te,
    const __hip_bfloat16* __restrict__ xlnT, const __hip_bfloat16* __restrict__ Wtg,
    float* __restrict__ tgp,
    const __hip_bfloat16* __restrict__ xg, const __hip_bfloat16* __restrict__ Wgt,
    float* __restrict__ gtv) {
  __shared__ char smem[24576];
  int bid = blockIdx.x;
  if (bid < 924) {
    int z = bid / 462, rem = bid - z*462;
    int n0 = (rem % 6)*64, m0 = (rem / 6)*128;
    mgemm_body(z ? hB_te : hB_se, 384, z ? Wte2 : Wse2, 384,
               z ? teb2 : seb2, z ? hA_te : hA_se, 384, 0,
               NROWS, 384, 0, 6, 1, 1, smem, m0, n0);
  } else if (bid < 1164) {
    int idx = bid - 924;
    int z = idx / 15, rem = idx - z*15;
    int n0 = (rem % 5)*64, m0 = (rem / 5)*128;
    int kt0 = z*10, kt1 = min(154, kt0 + 10);
    mgemm_body(xlnT, 9856, Wtg, 9856, nullptr, tgp, 320, (long)z*122880,
               384, 320, kt0, kt1, 0, 0, smem, m0, n0);
  } else {
    int m0 = (bid - 1164)*128;
    mgemm_body(xg, 384, Wgt, 384, nullptr, gtv, 12, 0,
               NROWS, 12, 0, 6, 0, 0, smem, m0, 0);
  }
}

// ============ F4: L3 GEMM se/te [0,154) + tgred [154,274)
__global__ __launch_bounds__(256) void k_f4(
    const __hip_bfloat16* __restrict__ hA_se, const __hip_bfloat16* __restrict__ hA_te,
    const __hip_bfloat16* __restrict__ Wse3, const __hip_bfloat16* __restrict__ Wte3,
    const float* __restrict__ seb3, const float* __restrict__ teb3,
    float* __restrict__ x1, float* __restrict__ x2,
    const float* __restrict__ tgp, float* __restrict__ tgv) {
  __shared__ char smem[24576];
  int bid = blockIdx.x;
  if (bid < 154) {
    int z = bid / 77, m0 = (bid - z*77)*128;
    mgemm_body(z ? hA_te : hA_se, 384, z ? Wte3 : Wse3, 384,
               z ? teb3 : seb3, z ? x2 : x1, 12, 0,
               NROWS, 12, 0, 6, 0, 0, smem, m0, 0);
  } else {
    int base = (bid - 154) * 1024;
    #pragma unroll
    for (int q = 0; q < 4; q++) {
      int gid = base + q*256 + threadIdx.x;
      float s = 0.f;
      #pragma unroll
      for (int z = 0; z < 16; z++) s += tgp[(size_t)z*122880 + gid];
      tgv[gid] = s;
    }
  }
}

// ============ F5: gates + fully_w + scale
__global__ __launch_bounds__(256) void k_final(const float* __restrict__ tgv,
    const float* __restrict__ gt, const float* __restrict__ x1,
    const float* __restrict__ x2, const float* __restrict__ fw,
    float* __restrict__ out) {
  __shared__ float w[288];
  for (int idx = threadIdx.x; idx < 288; idx += 256) w[idx] = fw[idx];
  __syncthreads();
  int gid = blockIdx.x*256 + threadIdx.x;
  if (gid >= NROWS) return;
  int b = gid / GDIM, g = gid - b*GDIM;
  float g1[12], g2[12];
  #pragma unroll
  for (int n = 0; n < 12; n++) {
    float tv  = tgv[(size_t)(b*12+n)*320 + g];
    float x1v = x1[(size_t)gid*12 + n];
    float gv  = gt[(size_t)gid*12 + n];
    float x2v = x2[(size_t)gid*12 + n];
    float s1 = 1.f/(1.f + __expf(-tv));
    float s2 = 1.f/(1.f + __expf(-gv));
    g1[n] = (tv + x1v)*s1;
    g2[n] = (gv + x2v)*s2;
  }
  #pragma unroll
  for (int o = 0; o < 12; o++) {
    float acc = 0.f;
    #pragma unroll
    for (int n = 0; n < 12; n++)
      acc += g1[n]*w[n*12+o] + g2[n]*w[(12+n)*12+o];
    out[(size_t)(b*12+o)*GDIM + g] = acc*50.f + 60.f;
  }
}

extern "C" void kernel_launch(void* const* d_in, const int* in_sizes, int n_in,
                              void* d_out, int out_size, void* d_ws, size_t ws_size,
                              hipStream_t stream) {
  const float* inp    = (const float*)d_in[0];
  const float* cw     = (const float*)d_in[1];
  const float* cb     = (const float*)d_in[2];
  const float* dws    = (const float*)d_in[3];
  const float* dbs    = (const float*)d_in[4];
  const float* ln_g   = (const float*)d_in[5];
  const float* ln_b   = (const float*)d_in[6];
  const float* tge2tg = (const float*)d_in[7];
  const float* gte2gt = (const float*)d_in[8];
  const float* fullyw = (const float*)d_in[9];
  const float* se[8];
  const float* te[8];
  for (int i = 0; i < 8; i++) { se[i] = (const float*)d_in[10+i]; te[i] = (const float*)d_in[18+i]; }
  float* out = (float*)d_out;

  // ---- workspace carve (~64 MB, no aliasing) ----
  char* base = (char*)d_ws;
  size_t off = 0;
  auto alloc = [&](size_t bytes) { char* r = base + off; off += (bytes + 255) & ~(size_t)255; return r; };
  float* A_pre = (float*)alloc(147456*4);
  float* Cp    = (float*)alloc(147456*4);
  float* x1    = (float*)alloc(117888*4);
  float* x2    = (float*)alloc(117888*4);
  float* gtv   = (float*)alloc(117888*4);
  float* tgv   = (float*)alloc(122880*4);
  float* tgp   = (float*)alloc((size_t)16*122880*4);
  __hip_bfloat16* hA_se = (__hip_bfloat16*)alloc((size_t)MPAD*384*2);
  __hip_bfloat16* hA_te = (__hip_bfloat16*)alloc((size_t)MPAD*384*2);
  __hip_bfloat16* hB_se = (__hip_bfloat16*)alloc((size_t)MPAD*384*2);
  __hip_bfloat16* hB_te = (__hip_bfloat16*)alloc((size_t)MPAD*384*2);
  __hip_bfloat16* xlnT  = (__hip_bfloat16*)alloc((size_t)384*9856*2);
  __hip_bfloat16* xg    = (__hip_bfloat16*)alloc((size_t)MPAD*384*2);
  __hip_bfloat16* Wse1 = (__hip_bfloat16*)alloc(147456*2);
  __hip_bfloat16* Wse2 = (__hip_bfloat16*)alloc(147456*2);
  __hip_bfloat16* Wte1 = (__hip_bfloat16*)alloc(147456*2);
  __hip_bfloat16* Wte2 = (__hip_bfloat16*)alloc(147456*2);
  __hip_bfloat16* Wse3 = (__hip_bfloat16*)alloc(24576*2);
  __hip_bfloat16* Wte3 = (__hip_bfloat16*)alloc(24576*2);
  __hip_bfloat16* Wgt  = (__hip_bfloat16*)alloc(24576*2);
  __hip_bfloat16* Wtg  = (__hip_bfloat16*)alloc((size_t)320*9856*2);

  // F1: transposes + layer-0(chunked) + prep
  k_f1<<<1624, 256, 0, stream>>>(inp, dws, cw, cb, A_pre, Cp,
      se[2], se[4], te[2], te[4], se[6], te[6], gte2gt, tge2tg,
      Wse1, Wse2, Wte1, Wte2, Wse3, Wte3, Wgt, Wtg,
      se[0], se[1], te[0], te[1], hA_se, hA_te);

  // F2: L1 GEMMs + xln(chunked)
  k_f2<<<2172, 256, 0, stream>>>(hA_se, hA_te, Wse1, Wte1, se[3], te[3],
      hB_se, hB_te, inp, dbs, A_pre, Cp, ln_g, ln_b, xlnT, xg);

  // F3: L2 GEMMs + tg split-K + gt
  k_f3<<<1241, 256, 0, stream>>>(hB_se, hB_te, Wse2, Wte2, se[5], te[5],
      hA_se, hA_te, xlnT, Wtg, tgp, xg, Wgt, gtv);

  // F4: L3 GEMMs + tg partial reduction
  k_f4<<<274, 256, 0, stream>>>(hA_se, hA_te, Wse3, Wte3, se[7], te[7], x1, x2, tgp, tgv);

  // F5: gates + output
  k_final<<<39, 256, 0, stream>>>(tgv, gtv, x1, x2, fullyw, out);
}